// Round 1
// baseline (820.632 us; speedup 1.0000x reference)
//
#include <hip/hip_runtime.h>
#include <math.h>

// Problem constants
#define BB 32
#define NN 8192
#define CC 64
#define SS 64    // NUM_NODE
#define KK 64    // NSAMPLE

// Workspace layout (in floats)
#define WS_FIDX   0         // int[2048]
#define WS_FLOC   2048      // float[2048*3]
#define WS_FFEA   8192      // float[2048*64]
#define WS_GIDX   139264    // int[2048*64]
#define WS_NLOC   270336    // float[2048*3]
#define WS_GIDX2  276480    // int[2048*64]
#define WS_PART   407552    // float[512*4160]
#define WS_TOT    2537472   // float[4160]
#define WS_SCALE  2541632   // float[64]
#define WS_SHIFT  2541696   // float[64]

// ---------------------------------------------------------------------------
// 1. Farthest point sampling: one block per batch. Bitwise-exact replication
//    of the reference arithmetic (no fp contraction, first-index argmax ties).
// ---------------------------------------------------------------------------
__global__ __launch_bounds__(256) void fps_kernel(const float* __restrict__ loc,
                                                  int* __restrict__ fidx) {
#pragma clang fp contract(off)
  int b = blockIdx.x, t = threadIdx.x;
  const float* lb = loc + (size_t)b * 3 * NN;
  float px[32], py[32], pz[32], dist[32];
#pragma unroll
  for (int k = 0; k < 32; k++) {
    int p = t + 256 * k;
    px[k] = lb[p]; py[k] = lb[NN + p]; pz[k] = lb[2 * NN + p];
    dist[k] = 1e10f;
  }
  __shared__ float cent[3];
  __shared__ float wrv[4];
  __shared__ int wri[4];
  int lane = t & 63, w = t >> 6;
  int far = 0;
  for (int it = 0; it < 64; it++) {
    if (t == 0) fidx[b * 64 + it] = far;
    if (t == (far & 255)) {
      int kk = far >> 8;
      cent[0] = px[kk]; cent[1] = py[kk]; cent[2] = pz[kk];
    }
    __syncthreads();
    float cx = cent[0], cy = cent[1], cz = cent[2];
    float bv = -1.0f; int bi = 0;
#pragma unroll
    for (int k = 0; k < 32; k++) {
      float dx = px[k] - cx, dy = py[k] - cy, dz = pz[k] - cz;
      float d = (dx * dx + dy * dy) + dz * dz;
      float dm = dist[k];
      dm = d < dm ? d : dm;
      dist[k] = dm;
      int p = t + 256 * k;
      if (dm > bv) { bv = dm; bi = p; }   // ascending p within thread: first-max kept
    }
    float v = bv; int vi = bi;
#pragma unroll
    for (int off = 32; off; off >>= 1) {
      float v2 = __shfl_xor(v, off, 64);
      int   i2 = __shfl_xor(vi, off, 64);
      if (v2 > v || (v2 == v && i2 < vi)) { v = v2; vi = i2; }
    }
    if (lane == 0) { wrv[w] = v; wri[w] = vi; }
    __syncthreads();
    float gv = wrv[0]; int gi = wri[0];
    for (int w2 = 1; w2 < 4; w2++) {
      float v2 = wrv[w2]; int i2 = wri[w2];
      if (v2 > gv || (v2 == gv && i2 < gi)) { gv = v2; gi = i2; }
    }
    far = gi;
  }
}

// ---------------------------------------------------------------------------
// 2. Gather fpoint_loc / fpoint_fea
// ---------------------------------------------------------------------------
__global__ __launch_bounds__(64) void gather_kernel(const float* __restrict__ loc,
                                                    const float* __restrict__ fea,
                                                    const int* __restrict__ fidx,
                                                    float* __restrict__ floc,
                                                    float* __restrict__ ffea) {
  int bs = blockIdx.x, b = bs >> 6, c = threadIdx.x;
  int g = fidx[bs];
  ffea[bs * 64 + c] = fea[(size_t)b * (CC * NN) + (size_t)c * NN + g];
  if (c < 3) floc[bs * 3 + c] = loc[(size_t)b * (3 * NN) + (size_t)c * NN + g];
}

// ---------------------------------------------------------------------------
// 3. Ball query (radius): first up-to-64 in-radius points by ascending index,
//    padded with the first hit. One block per (b,s).
// ---------------------------------------------------------------------------
__global__ __launch_bounds__(256) void ball1_kernel(const float* __restrict__ loc,
                                                    const float* __restrict__ floc,
                                                    int* __restrict__ gidx) {
#pragma clang fp contract(off)
  int bs = blockIdx.x, b = bs >> 6, t = threadIdx.x;
  const float* lb = loc + (size_t)b * 3 * NN;
  float ax = floc[bs * 3], ay = floc[bs * 3 + 1], az = floc[bs * 3 + 2];
  float A = (ax * ax + ay * ay) + az * az;
  unsigned mask = 0u;
  int base = t * 32;
  for (int jj = 0; jj < 32; jj++) {
    int p = base + jj;
    float bx = lb[p], by = lb[NN + p], bz = lb[2 * NN + p];
    float Bn = (bx * bx + by * by) + bz * bz;
    float dot = fmaf(az, bz, fmaf(ay, by, ax * bx));
    float sqr = (A + Bn) - 2.0f * dot;
    if (!(sqr > 0.09f)) mask |= (1u << jj);
  }
  __shared__ int cnt[256];
  __shared__ int firsth;
  int pop = __popc(mask);
  cnt[t] = pop;
  __syncthreads();
  for (int off = 1; off < 256; off <<= 1) {   // inclusive Hillis-Steele scan
    int add = (t >= off) ? cnt[t - off] : 0;
    __syncthreads();
    cnt[t] += add;
    __syncthreads();
  }
  int excl = cnt[t] - pop;
  int total = cnt[255];
  unsigned m = mask; int pos = excl;
  while (m) {
    int jj = __ffs(m) - 1; m &= m - 1;
    int p = base + jj;
    if (pos == 0) firsth = p;
    if (pos < 64) gidx[bs * 64 + pos] = p;
    pos++;
  }
  __syncthreads();
  if (total < 64 && t >= total && t < 64) gidx[bs * 64 + t] = firsth;
}

// ---------------------------------------------------------------------------
// 4. seman = tanh(pred_w . group_fea); node_offset = mean_k(seman*group_loc);
//    node_loc = fpoint_loc + node_offset. One wave per (b,s), lane = k.
// ---------------------------------------------------------------------------
__global__ __launch_bounds__(64) void seman_kernel(const float* __restrict__ fea,
                                                   const float* __restrict__ loc,
                                                   const float* __restrict__ pw,
                                                   const int* __restrict__ gidx,
                                                   const float* __restrict__ ffea,
                                                   const float* __restrict__ floc,
                                                   float* __restrict__ out_noff,
                                                   float* __restrict__ nloc) {
  int bs = blockIdx.x, b = bs >> 6, s = bs & 63, k = threadIdx.x;
  __shared__ float sf[64];
  __shared__ float spw[192];
  __shared__ float sl[3];
  sf[k] = ffea[bs * 64 + k];
  spw[k] = pw[k]; spw[64 + k] = pw[64 + k]; spw[128 + k] = pw[128 + k];
  if (k < 3) sl[k] = floc[bs * 3 + k];
  __syncthreads();
  int g = gidx[bs * 64 + k];
  const float* fb = fea + (size_t)b * (CC * NN);
  float a0 = 0.f, a1 = 0.f, a2 = 0.f;
  for (int c = 0; c < 64; c++) {
    float gf = fb[(size_t)c * NN + g] - sf[c];
    a0 = fmaf(spw[c], gf, a0);
    a1 = fmaf(spw[64 + c], gf, a1);
    a2 = fmaf(spw[128 + c], gf, a2);
  }
  const float* lb = loc + (size_t)b * 3 * NN;
  float c0 = tanhf(a0) * (lb[g] - sl[0]);
  float c1 = tanhf(a1) * (lb[NN + g] - sl[1]);
  float c2 = tanhf(a2) * (lb[2 * NN + g] - sl[2]);
#pragma unroll
  for (int off = 32; off; off >>= 1) {
    c0 += __shfl_xor(c0, off, 64);
    c1 += __shfl_xor(c1, off, 64);
    c2 += __shfl_xor(c2, off, 64);
  }
  if (k == 0) {
    float m0 = c0 * (1.0f / 64), m1 = c1 * (1.0f / 64), m2 = c2 * (1.0f / 64);
    out_noff[b * 192 + s] = m0;
    out_noff[b * 192 + 64 + s] = m1;
    out_noff[b * 192 + 128 + s] = m2;
    nloc[bs * 3 + 0] = sl[0] + m0;
    nloc[bs * 3 + 1] = sl[1] + m1;
    nloc[bs * 3 + 2] = sl[2] + m2;
  }
}

// ---------------------------------------------------------------------------
// 5. kNN-64 (stable argsort semantics): distances into LDS, 64 rounds of
//    incremental argmin (lexicographic (value, index) = stable sort order).
// ---------------------------------------------------------------------------
__global__ __launch_bounds__(256) void knn_kernel(const float* __restrict__ loc,
                                                  const float* __restrict__ nloc,
                                                  int* __restrict__ gidx2) {
#pragma clang fp contract(off)
  int bs = blockIdx.x, b = bs >> 6, t = threadIdx.x;
  const float* lb = loc + (size_t)b * 3 * NN;
  float ax = nloc[bs * 3], ay = nloc[bs * 3 + 1], az = nloc[bs * 3 + 2];
  float A = (ax * ax + ay * ay) + az * az;
  __shared__ float dist[NN];
  for (int k = 0; k < 32; k++) {
    int p = t + 256 * k;
    float bx = lb[p], by = lb[NN + p], bz = lb[2 * NN + p];
    float Bn = (bx * bx + by * by) + bz * bz;
    float dot = fmaf(az, bz, fmaf(ay, by, ax * bx));
    dist[p] = (A + Bn) - 2.0f * dot;
  }
  __syncthreads();
  int base = t * 32;
  float lv = 1e30f; int li = base;
  for (int jj = 0; jj < 32; jj++) {
    float d = dist[base + jj];
    if (d < lv) { lv = d; li = base + jj; }
  }
  __shared__ float wrv[4];
  __shared__ int wri[4];
  __shared__ int winner;
  int lane = t & 63, w = t >> 6;
  for (int r = 0; r < 64; r++) {
    float v = lv; int vi = li;
#pragma unroll
    for (int off = 1; off < 64; off <<= 1) {
      float v2 = __shfl_xor(v, off, 64);
      int   i2 = __shfl_xor(vi, off, 64);
      if (v2 < v || (v2 == v && i2 < vi)) { v = v2; vi = i2; }
    }
    if (lane == 0) { wrv[w] = v; wri[w] = vi; }
    __syncthreads();
    if (t == 0) {
      float gv = wrv[0]; int gi = wri[0];
      for (int w2 = 1; w2 < 4; w2++) {
        if (wrv[w2] < gv || (wrv[w2] == gv && wri[w2] < gi)) { gv = wrv[w2]; gi = wri[w2]; }
      }
      winner = gi;
      gidx2[bs * 64 + r] = gi;
    }
    __syncthreads();
    int win = winner;
    if ((win >> 5) == t) {           // owner: extract and rescan its slice
      dist[win] = 1e30f;
      lv = 1e30f; li = base;
      for (int jj = 0; jj < 32; jj++) {
        float d = dist[base + jj];
        if (d < lv) { lv = d; li = base + jj; }
      }
    }
  }
}

// ---------------------------------------------------------------------------
// 6. Input channel covariance (for BN stats of the linear layer).
//    512 blocks x 4 chunks of 128 points; per-wave full 64x64 tile, 8x8/lane.
// ---------------------------------------------------------------------------
__global__ __launch_bounds__(256) void cov_kernel(const float* __restrict__ fea,
                                                  float* __restrict__ part) {
  __shared__ float Sf[64 * 133];
  __shared__ float red[4160];
  int t = threadIdx.x, w = t >> 6, lane = t & 63;
  int i = lane >> 3, j = lane & 7;
  float acc[8][8];
  float rs[8];
#pragma unroll
  for (int r = 0; r < 8; r++) {
    rs[r] = 0.f;
#pragma unroll
    for (int r2 = 0; r2 < 8; r2++) acc[r][r2] = 0.f;
  }
  for (int q = 0; q < 4; q++) {
    int chunk = blockIdx.x * 4 + q;
    int p0 = chunk * 128;
    int b = p0 >> 13, n0 = p0 & 8191;
    __syncthreads();
    const float* fb = fea + (size_t)b * (CC * NN) + n0;
    for (int m = 0; m < 32; m++) {
      int idx = m * 256 + t;
      int c = idx >> 7, pt = idx & 127;
      Sf[c * 133 + pt] = fb[(size_t)c * NN + pt];
    }
    __syncthreads();
    for (int pt = w * 32; pt < w * 32 + 32; pt++) {
      float a[8], bv[8];
#pragma unroll
      for (int r = 0; r < 8; r++) {
        a[r] = Sf[(8 * i + r) * 133 + pt];
        bv[r] = Sf[(8 * j + r) * 133 + pt];
      }
#pragma unroll
      for (int r = 0; r < 8; r++) {
        rs[r] += a[r];
#pragma unroll
        for (int r2 = 0; r2 < 8; r2++) acc[r][r2] = fmaf(a[r], bv[r2], acc[r][r2]);
      }
    }
  }
  for (int ww = 0; ww < 4; ww++) {
    if (w == ww) {
#pragma unroll
      for (int r = 0; r < 8; r++) {
#pragma unroll
        for (int r2 = 0; r2 < 8; r2++) {
          int idx = (8 * i + r) * 64 + 8 * j + r2;
          if (ww == 0) red[idx] = acc[r][r2]; else red[idx] += acc[r][r2];
        }
        if (j == 0) {
          int ridx = 4096 + 8 * i + r;
          if (ww == 0) red[ridx] = rs[r]; else red[ridx] += rs[r];
        }
      }
    }
    __syncthreads();
  }
  float* pb = part + (size_t)blockIdx.x * 4160;
  for (int idx = t; idx < 4160; idx += 256) pb[idx] = red[idx];
}

__global__ __launch_bounds__(256) void covreduce_kernel(const float* __restrict__ part,
                                                        float* __restrict__ tot) {
  int e = blockIdx.x * 256 + threadIdx.x;
  if (e >= 4160) return;
  float s = 0.f;
  for (int b2 = 0; b2 < 512; b2++) s += part[(size_t)b2 * 4160 + e];
  tot[e] = s;
}

// ---------------------------------------------------------------------------
// 7. BN stats: res = W f + b is linear -> mean/var from channel moments of f.
// ---------------------------------------------------------------------------
__global__ __launch_bounds__(64) void bnstats_kernel(const float* __restrict__ tot,
                                                     const float* __restrict__ rw,
                                                     const float* __restrict__ rb,
                                                     const float* __restrict__ gam,
                                                     const float* __restrict__ bet,
                                                     float* __restrict__ bnsc,
                                                     float* __restrict__ bnsh) {
  int o = threadIdx.x;
  const float invM = 1.0f / 262144.0f;
  float mu = 0.f;
  for (int c = 0; c < 64; c++) mu += rw[o * 64 + c] * (tot[4096 + c] * invM);
  float exx = 0.f;
  for (int c = 0; c < 64; c++) {
    const float* row = tot + c * 64;
    float p = 0.f;
    for (int c2 = 0; c2 < 64; c2++) p += rw[o * 64 + c2] * row[c2];
    exx += rw[o * 64 + c] * p;
  }
  exx *= invM;
  float var = exx - mu * mu;
  float mean = mu + rb[o];
  float sc = gam[o] / sqrtf(var + 1e-5f);
  bnsc[o] = sc;
  bnsh[o] = bet[o] - mean * sc;
}

// ---------------------------------------------------------------------------
// 8. node_fea = max_k relu(BN(W . fea[gidx2])). One block per (b,s).
//    W row per lane in registers; gathered features staged in LDS, float4 reads.
// ---------------------------------------------------------------------------
__global__ __launch_bounds__(256) void nodefea_kernel(const float* __restrict__ fea,
                                                      const float* __restrict__ rw,
                                                      const int* __restrict__ gidx2,
                                                      const float* __restrict__ bnsc,
                                                      const float* __restrict__ bnsh,
                                                      float* __restrict__ out_nf) {
  __shared__ __align__(16) float Lf[4096];  // [k][c]
  __shared__ float Lw[4096];                // [c][o] = rw[o][c]
  __shared__ int Lg[64];
  __shared__ float red[256];
  int bs = blockIdx.x, b = bs >> 6, s = bs & 63, t = threadIdx.x;
  if (t < 64) Lg[t] = gidx2[bs * 64 + t];
  __syncthreads();
  const float* fb = fea + (size_t)b * (CC * NN);
  for (int m = 0; m < 16; m++) {
    int idx = m * 256 + t;
    int k = idx >> 6, c = idx & 63;
    Lf[idx] = fb[(size_t)c * NN + Lg[k]];
    Lw[idx] = rw[(idx & 63) * 64 + (idx >> 6)];
  }
  __syncthreads();
  int o = t & 63, wq = t >> 6;
  float wreg[64];
#pragma unroll
  for (int c = 0; c < 64; c++) wreg[c] = Lw[c * 64 + o];
  float sc = bnsc[o], sh = bnsh[o];
  float mx = -1e30f;
  for (int k = wq * 16; k < wq * 16 + 16; k++) {
    float raw = 0.f;
#pragma unroll
    for (int c4 = 0; c4 < 16; c4++) {
      float4 lf = *(const float4*)&Lf[k * 64 + c4 * 4];
      raw = fmaf(wreg[4 * c4 + 0], lf.x, raw);
      raw = fmaf(wreg[4 * c4 + 1], lf.y, raw);
      raw = fmaf(wreg[4 * c4 + 2], lf.z, raw);
      raw = fmaf(wreg[4 * c4 + 3], lf.w, raw);
    }
    float v = raw * sc + sh;
    v = v > 0.f ? v : 0.f;
    mx = v > mx ? v : mx;
  }
  red[wq * 64 + o] = mx;
  __syncthreads();
  if (t < 64) {
    float m0 = red[t], m1 = red[64 + t], m2 = red[128 + t], m3 = red[192 + t];
    float ma = m0 > m1 ? m0 : m1;
    float mb = m2 > m3 ? m2 : m3;
    float m = ma > mb ? ma : mb;
    out_nf[b * 4096 + t * 64 + s] = m;   // node_fea[b][o=t][s]
  }
}

// ---------------------------------------------------------------------------
// 9. 3-NN inverse-distance interpolation + input_fea passthrough (output asm).
//    One thread per (b, n).
// ---------------------------------------------------------------------------
__global__ __launch_bounds__(256) void interp_kernel(const float* __restrict__ fea,
                                                     const float* __restrict__ loc,
                                                     const float* __restrict__ nloc,
                                                     const float* __restrict__ nf,
                                                     float* __restrict__ out) {
#pragma clang fp contract(off)
  int b = blockIdx.y;
  int t = threadIdx.x;
  int n = blockIdx.x * 256 + t;
  __shared__ float snl[192];
  __shared__ float sB[64];
  if (t < 192) snl[t] = nloc[b * 192 + t];
  __syncthreads();
  if (t < 64) {
    float x = snl[t * 3], y = snl[t * 3 + 1], z = snl[t * 3 + 2];
    sB[t] = (x * x + y * y) + z * z;
  }
  __syncthreads();
  const float* lb = loc + (size_t)b * 3 * NN;
  float px = lb[n], py = lb[NN + n], pz = lb[2 * NN + n];
  float A = (px * px + py * py) + pz * pz;
  float d0 = 1e30f, d1 = 1e30f, d2 = 1e30f;
  int i0 = 0, i1 = 0, i2 = 0;
  for (int s = 0; s < 64; s++) {
    float dot = fmaf(pz, snl[s * 3 + 2], fmaf(py, snl[s * 3 + 1], px * snl[s * 3]));
    float d = (A + sB[s]) - 2.0f * dot;
    if (d < d0) { d2 = d1; i2 = i1; d1 = d0; i1 = i0; d0 = d; i0 = s; }
    else if (d < d1) { d2 = d1; i2 = i1; d1 = d; i1 = s; }
    else if (d < d2) { d2 = d; i2 = s; }
  }
  d0 = d0 > 1e-10f ? d0 : 1e-10f;
  d1 = d1 > 1e-10f ? d1 : 1e-10f;
  d2 = d2 > 1e-10f ? d2 : 1e-10f;
  float r0 = 1.0f / d0, r1 = 1.0f / d1, r2 = 1.0f / d2;
  float rsum = (r0 + r1) + r2;
  float w0 = r0 / rsum, w1 = r1 / rsum, w2 = r2 / rsum;
  const float* nfb = nf + b * 4096;
  const float* fb = fea + (size_t)b * (CC * NN);
  float* ob = out + (size_t)b * (128 * NN);
  for (int o = 0; o < 64; o++) {
    ob[(size_t)o * NN + n] = fb[(size_t)o * NN + n];
    float ip = (nfb[o * 64 + i0] * w0 + nfb[o * 64 + i1] * w1) + nfb[o * 64 + i2] * w2;
    ob[(size_t)(64 + o) * NN + n] = ip;
  }
}

// ---------------------------------------------------------------------------
extern "C" void kernel_launch(void* const* d_in, const int* in_sizes, int n_in,
                              void* d_out, int out_size, void* d_ws, size_t ws_size,
                              hipStream_t stream) {
  (void)in_sizes; (void)n_in; (void)out_size; (void)ws_size;
  const float* fea = (const float*)d_in[0];
  const float* loc = (const float*)d_in[1];
  const float* pw  = (const float*)d_in[2];
  const float* rw  = (const float*)d_in[3];
  const float* rb  = (const float*)d_in[4];
  const float* gam = (const float*)d_in[5];
  const float* bet = (const float*)d_in[6];
  float* out = (float*)d_out;
  float* ws = (float*)d_ws;

  int*   fidx  = (int*)(ws + WS_FIDX);
  float* floc  = ws + WS_FLOC;
  float* ffea  = ws + WS_FFEA;
  int*   gidx  = (int*)(ws + WS_GIDX);
  float* nlocp = ws + WS_NLOC;
  int*   gidx2 = (int*)(ws + WS_GIDX2);
  float* part  = ws + WS_PART;
  float* tot   = ws + WS_TOT;
  float* bnsc  = ws + WS_SCALE;
  float* bnsh  = ws + WS_SHIFT;

  float* out_nf   = out + 33554432;  // node_fea   (B,64,64,1)
  float* out_noff = out + 33685504;  // node_offset(B,3,64)

  fps_kernel<<<dim3(32), dim3(256), 0, stream>>>(loc, fidx);
  gather_kernel<<<dim3(2048), dim3(64), 0, stream>>>(loc, fea, fidx, floc, ffea);
  ball1_kernel<<<dim3(2048), dim3(256), 0, stream>>>(loc, floc, gidx);
  seman_kernel<<<dim3(2048), dim3(64), 0, stream>>>(fea, loc, pw, gidx, ffea, floc, out_noff, nlocp);
  knn_kernel<<<dim3(2048), dim3(256), 0, stream>>>(loc, nlocp, gidx2);
  cov_kernel<<<dim3(512), dim3(256), 0, stream>>>(fea, part);
  covreduce_kernel<<<dim3(17), dim3(256), 0, stream>>>(part, tot);
  bnstats_kernel<<<dim3(1), dim3(64), 0, stream>>>(tot, rw, rb, gam, bet, bnsc, bnsh);
  nodefea_kernel<<<dim3(2048), dim3(256), 0, stream>>>(fea, rw, gidx2, bnsc, bnsh, out_nf);
  interp_kernel<<<dim3(32, 32), dim3(256), 0, stream>>>(fea, loc, nlocp, out_nf, out);
}

// Round 2
// 719.295 us; speedup vs baseline: 1.1409x; 1.1409x over previous
//
#include <hip/hip_runtime.h>
#include <math.h>

// Problem constants
#define BB 32
#define NN 8192
#define CC 64
#define SS 64    // NUM_NODE
#define KK 64    // NSAMPLE

// Workspace layout (in floats)
#define WS_FIDX   0         // int[2048]
#define WS_FLOC   2048      // float[2048*3]
#define WS_FFEA   8192      // float[2048*64]
#define WS_GIDX   139264    // int[2048*64]
#define WS_NLOC   270336    // float[2048*3]
#define WS_GIDX2  276480    // int[2048*64]
#define WS_PART   407552    // float[512*4160]
#define WS_TOT    2537472   // float[4160]
#define WS_SCALE  2541632   // float[64]
#define WS_SHIFT  2541696   // float[64]

// ---------------------------------------------------------------------------
// 1. Farthest point sampling: one block per batch. Bitwise-exact replication
//    of the reference arithmetic (no fp contraction, first-index argmax ties).
// ---------------------------------------------------------------------------
__global__ __launch_bounds__(256) void fps_kernel(const float* __restrict__ loc,
                                                  int* __restrict__ fidx) {
#pragma clang fp contract(off)
  int b = blockIdx.x, t = threadIdx.x;
  const float* lb = loc + (size_t)b * 3 * NN;
  float px[32], py[32], pz[32], dist[32];
#pragma unroll
  for (int k = 0; k < 32; k++) {
    int p = t + 256 * k;
    px[k] = lb[p]; py[k] = lb[NN + p]; pz[k] = lb[2 * NN + p];
    dist[k] = 1e10f;
  }
  __shared__ float cent[3];
  __shared__ float wrv[4];
  __shared__ int wri[4];
  int lane = t & 63, w = t >> 6;
  int far = 0;
  for (int it = 0; it < 64; it++) {
    if (t == 0) fidx[b * 64 + it] = far;
    if (t == (far & 255)) {
      int kk = far >> 8;
      cent[0] = px[kk]; cent[1] = py[kk]; cent[2] = pz[kk];
    }
    __syncthreads();
    float cx = cent[0], cy = cent[1], cz = cent[2];
    float bv = -1.0f; int bi = 0;
#pragma unroll
    for (int k = 0; k < 32; k++) {
      float dx = px[k] - cx, dy = py[k] - cy, dz = pz[k] - cz;
      float d = (dx * dx + dy * dy) + dz * dz;
      float dm = dist[k];
      dm = d < dm ? d : dm;
      dist[k] = dm;
      int p = t + 256 * k;
      if (dm > bv) { bv = dm; bi = p; }   // ascending p within thread: first-max kept
    }
    float v = bv; int vi = bi;
#pragma unroll
    for (int off = 32; off; off >>= 1) {
      float v2 = __shfl_xor(v, off, 64);
      int   i2 = __shfl_xor(vi, off, 64);
      if (v2 > v || (v2 == v && i2 < vi)) { v = v2; vi = i2; }
    }
    if (lane == 0) { wrv[w] = v; wri[w] = vi; }
    __syncthreads();
    float gv = wrv[0]; int gi = wri[0];
    for (int w2 = 1; w2 < 4; w2++) {
      float v2 = wrv[w2]; int i2 = wri[w2];
      if (v2 > gv || (v2 == gv && i2 < gi)) { gv = v2; gi = i2; }
    }
    far = gi;
  }
}

// ---------------------------------------------------------------------------
// 2. Gather fpoint_loc / fpoint_fea
// ---------------------------------------------------------------------------
__global__ __launch_bounds__(64) void gather_kernel(const float* __restrict__ loc,
                                                    const float* __restrict__ fea,
                                                    const int* __restrict__ fidx,
                                                    float* __restrict__ floc,
                                                    float* __restrict__ ffea) {
  int bs = blockIdx.x, b = bs >> 6, c = threadIdx.x;
  int g = fidx[bs];
  ffea[bs * 64 + c] = fea[(size_t)b * (CC * NN) + (size_t)c * NN + g];
  if (c < 3) floc[bs * 3 + c] = loc[(size_t)b * (3 * NN) + (size_t)c * NN + g];
}

// ---------------------------------------------------------------------------
// 3. Ball query (radius): first up-to-64 in-radius points by ascending index,
//    padded with the first hit. ONE WAVE per (b,s); wave-synchronous ballot
//    compaction with early exit (no barriers). Order within gidx is only
//    consumed by a mean, so index-ascending compaction order is fine.
// ---------------------------------------------------------------------------
__global__ __launch_bounds__(256) void ball1_kernel(const float* __restrict__ loc,
                                                    const float* __restrict__ floc,
                                                    int* __restrict__ gidx) {
#pragma clang fp contract(off)
  int w = threadIdx.x >> 6, lane = threadIdx.x & 63;
  int bs = blockIdx.x * 4 + w, b = bs >> 6;
  const float* lb = loc + (size_t)b * 3 * NN;
  float ax = floc[bs * 3], ay = floc[bs * 3 + 1], az = floc[bs * 3 + 2];
  float A = (ax * ax + ay * ay) + az * az;
  int count = 0, firsth = -1;
  for (int ch = 0; ch < 128 && count < 64; ch++) {
    int p = ch * 64 + lane;
    float bx = lb[p], by = lb[NN + p], bz = lb[2 * NN + p];
    float Bn = (bx * bx + by * by) + bz * bz;
    float dot = fmaf(az, bz, fmaf(ay, by, ax * bx));
    float sqr = (A + Bn) - 2.0f * dot;
    bool hit = !(sqr > 0.09f);
    unsigned long long m = __ballot(hit);
    if (m) {
      if (firsth < 0) firsth = ch * 64 + (int)__ffsll(m) - 1;
      int pos = count + (int)__popcll(m & ((1ull << lane) - 1ull));
      if (hit && pos < 64) gidx[bs * 64 + pos] = p;
      count += (int)__popcll(m);
    }
  }
  if (count < 64 && lane >= count) gidx[bs * 64 + lane] = firsth;
}

// ---------------------------------------------------------------------------
// 4. seman = tanh(pred_w . group_fea); node_offset = mean_k(seman*group_loc);
//    node_loc = fpoint_loc + node_offset. One wave per (b,s), lane = k.
// ---------------------------------------------------------------------------
__global__ __launch_bounds__(64) void seman_kernel(const float* __restrict__ fea,
                                                   const float* __restrict__ loc,
                                                   const float* __restrict__ pw,
                                                   const int* __restrict__ gidx,
                                                   const float* __restrict__ ffea,
                                                   const float* __restrict__ floc,
                                                   float* __restrict__ out_noff,
                                                   float* __restrict__ nloc) {
  int bs = blockIdx.x, b = bs >> 6, s = bs & 63, k = threadIdx.x;
  __shared__ float sf[64];
  __shared__ float spw[192];
  __shared__ float sl[3];
  sf[k] = ffea[bs * 64 + k];
  spw[k] = pw[k]; spw[64 + k] = pw[64 + k]; spw[128 + k] = pw[128 + k];
  if (k < 3) sl[k] = floc[bs * 3 + k];
  __syncthreads();
  int g = gidx[bs * 64 + k];
  const float* fb = fea + (size_t)b * (CC * NN);
  float a0 = 0.f, a1 = 0.f, a2 = 0.f;
  for (int c = 0; c < 64; c++) {
    float gf = fb[(size_t)c * NN + g] - sf[c];
    a0 = fmaf(spw[c], gf, a0);
    a1 = fmaf(spw[64 + c], gf, a1);
    a2 = fmaf(spw[128 + c], gf, a2);
  }
  const float* lb = loc + (size_t)b * 3 * NN;
  float c0 = tanhf(a0) * (lb[g] - sl[0]);
  float c1 = tanhf(a1) * (lb[NN + g] - sl[1]);
  float c2 = tanhf(a2) * (lb[2 * NN + g] - sl[2]);
#pragma unroll
  for (int off = 32; off; off >>= 1) {
    c0 += __shfl_xor(c0, off, 64);
    c1 += __shfl_xor(c1, off, 64);
    c2 += __shfl_xor(c2, off, 64);
  }
  if (k == 0) {
    float m0 = c0 * (1.0f / 64), m1 = c1 * (1.0f / 64), m2 = c2 * (1.0f / 64);
    out_noff[b * 192 + s] = m0;
    out_noff[b * 192 + 64 + s] = m1;
    out_noff[b * 192 + 128 + s] = m2;
    nloc[bs * 3 + 0] = sl[0] + m0;
    nloc[bs * 3 + 1] = sl[1] + m1;
    nloc[bs * 3 + 2] = sl[2] + m2;
  }
}

// ---------------------------------------------------------------------------
// 5. kNN-64 via radix select (set semantics — gidx2 feeds only a max-pool,
//    so order is irrelevant; ties broken by (key,index) = stable-argsort set).
//    Monotonic u32 key; 4096-bin LDS histogram on key>>20; pivot bin located
//    once; definite winners compacted with an LDS counter; remaining R picked
//    from pivot-bin candidates by one wave. ~5 barriers vs 128 before.
// ---------------------------------------------------------------------------
__global__ __launch_bounds__(256) void knn_kernel(const float* __restrict__ loc,
                                                  const float* __restrict__ nloc,
                                                  int* __restrict__ gidx2) {
#pragma clang fp contract(off)
  int bs = blockIdx.x, b = bs >> 6, t = threadIdx.x;
  const float* lb = loc + (size_t)b * 3 * NN;
  float ax = nloc[bs * 3], ay = nloc[bs * 3 + 1], az = nloc[bs * 3 + 2];
  float A = (ax * ax + ay * ay) + az * az;
  __shared__ unsigned keys[NN];
  __shared__ unsigned hist[4096];          // reused as u16 cand[8192] later
  __shared__ unsigned part[256];
  __shared__ int sP, sC0, nOut, nCand;
  for (int m = 0; m < 16; m++) hist[m * 256 + t] = 0u;
  if (t == 0) { nOut = 0; nCand = 0; }
  __syncthreads();
  unsigned mykey[32];
#pragma unroll
  for (int k = 0; k < 32; k++) {
    int p = t + 256 * k;
    float bx = lb[p], by = lb[NN + p], bz = lb[2 * NN + p];
    float Bn = (bx * bx + by * by) + bz * bz;
    float dot = fmaf(az, bz, fmaf(ay, by, ax * bx));
    float d = (A + Bn) - 2.0f * dot;
    unsigned kb = __float_as_uint(d);
    kb = (kb & 0x80000000u) ? ~kb : (kb | 0x80000000u);   // monotonic transform
    mykey[k] = kb;
    keys[p] = kb;
    atomicAdd(&hist[kb >> 20], 1u);
  }
  __syncthreads();
  // partial sums: thread t owns bins [16t, 16t+16)
  unsigned ps = 0;
#pragma unroll
  for (int m = 0; m < 16; m++) ps += hist[t * 16 + m];
  part[t] = ps;
  __syncthreads();
  if (t == 0) {
    int cum = 0, seg = 0;
    for (int t2 = 0; t2 < 256; t2++) {
      if (cum + (int)part[t2] >= 64) { seg = t2; break; }
      cum += (int)part[t2];
    }
    int P = seg * 16;
    for (;; P++) {
      if (cum + (int)hist[P] >= 64) break;
      cum += (int)hist[P];
    }
    sP = P; sC0 = cum;
  }
  __syncthreads();
  int P = sP, C0 = sC0;
  unsigned short* cand = (unsigned short*)hist;   // hist dead past this point
  __syncthreads();                                 // protect reuse
#pragma unroll
  for (int k = 0; k < 32; k++) {
    int bin = (int)(mykey[k] >> 20);
    if (bin < P) {
      int pos = atomicAdd(&nOut, 1);
      gidx2[bs * 64 + pos] = t + 256 * k;
    } else if (bin == P) {
      int c = atomicAdd(&nCand, 1);
      cand[c] = (unsigned short)(t + 256 * k);
    }
  }
  __syncthreads();
  if (t < 64) {
    int lane = t;
    int R = 64 - C0, nC = nCand;
    for (int r = 0; r < R; r++) {
      unsigned bk = 0xFFFFFFFFu; int bp = 0x7FFFFFFF, bj = -1;
      for (int j = lane; j < nC; j += 64) {
        int p = cand[j];
        if (p != 0xFFFF) {
          unsigned k2 = keys[p];
          if (k2 < bk || (k2 == bk && p < bp)) { bk = k2; bp = p; bj = j; }
        }
      }
#pragma unroll
      for (int off = 1; off < 64; off <<= 1) {
        unsigned k2 = __shfl_xor(bk, off, 64);
        int p2 = __shfl_xor(bp, off, 64);
        int j2 = __shfl_xor(bj, off, 64);
        if (k2 < bk || (k2 == bk && p2 < bp)) { bk = k2; bp = p2; bj = j2; }
      }
      if (lane == 0) {
        gidx2[bs * 64 + C0 + r] = bp;
        cand[bj] = 0xFFFF;
      }
      __threadfence_block();   // order lane-0's LDS write before next scan
    }
  }
}

// ---------------------------------------------------------------------------
// 6. Input channel covariance (for BN stats of the linear layer).
//    512 blocks x 4 chunks of 128 points; per-wave full 64x64 tile, 8x8/lane.
// ---------------------------------------------------------------------------
__global__ __launch_bounds__(256) void cov_kernel(const float* __restrict__ fea,
                                                  float* __restrict__ part) {
  __shared__ float Sf[64 * 133];
  __shared__ float red[4160];
  int t = threadIdx.x, w = t >> 6, lane = t & 63;
  int i = lane >> 3, j = lane & 7;
  float acc[8][8];
  float rs[8];
#pragma unroll
  for (int r = 0; r < 8; r++) {
    rs[r] = 0.f;
#pragma unroll
    for (int r2 = 0; r2 < 8; r2++) acc[r][r2] = 0.f;
  }
  for (int q = 0; q < 4; q++) {
    int chunk = blockIdx.x * 4 + q;
    int p0 = chunk * 128;
    int b = p0 >> 13, n0 = p0 & 8191;
    __syncthreads();
    const float* fb = fea + (size_t)b * (CC * NN) + n0;
    for (int m = 0; m < 32; m++) {
      int idx = m * 256 + t;
      int c = idx >> 7, pt = idx & 127;
      Sf[c * 133 + pt] = fb[(size_t)c * NN + pt];
    }
    __syncthreads();
    for (int pt = w * 32; pt < w * 32 + 32; pt++) {
      float a[8], bv[8];
#pragma unroll
      for (int r = 0; r < 8; r++) {
        a[r] = Sf[(8 * i + r) * 133 + pt];
        bv[r] = Sf[(8 * j + r) * 133 + pt];
      }
#pragma unroll
      for (int r = 0; r < 8; r++) {
        rs[r] += a[r];
#pragma unroll
        for (int r2 = 0; r2 < 8; r2++) acc[r][r2] = fmaf(a[r], bv[r2], acc[r][r2]);
      }
    }
  }
  for (int ww = 0; ww < 4; ww++) {
    if (w == ww) {
#pragma unroll
      for (int r = 0; r < 8; r++) {
#pragma unroll
        for (int r2 = 0; r2 < 8; r2++) {
          int idx = (8 * i + r) * 64 + 8 * j + r2;
          if (ww == 0) red[idx] = acc[r][r2]; else red[idx] += acc[r][r2];
        }
        if (j == 0) {
          int ridx = 4096 + 8 * i + r;
          if (ww == 0) red[ridx] = rs[r]; else red[ridx] += rs[r];
        }
      }
    }
    __syncthreads();
  }
  float* pb = part + (size_t)blockIdx.x * 4160;
  for (int idx = t; idx < 4160; idx += 256) pb[idx] = red[idx];
}

__global__ __launch_bounds__(256) void covreduce_kernel(const float* __restrict__ part,
                                                        float* __restrict__ tot) {
  int e = blockIdx.x * 256 + threadIdx.x;
  if (e >= 4160) return;
  float s = 0.f;
  for (int b2 = 0; b2 < 512; b2++) s += part[(size_t)b2 * 4160 + e];
  tot[e] = s;
}

// ---------------------------------------------------------------------------
// 7. BN stats: res = W f + b is linear -> mean/var from channel moments of f.
// ---------------------------------------------------------------------------
__global__ __launch_bounds__(64) void bnstats_kernel(const float* __restrict__ tot,
                                                     const float* __restrict__ rw,
                                                     const float* __restrict__ rb,
                                                     const float* __restrict__ gam,
                                                     const float* __restrict__ bet,
                                                     float* __restrict__ bnsc,
                                                     float* __restrict__ bnsh) {
  int o = threadIdx.x;
  const float invM = 1.0f / 262144.0f;
  float mu = 0.f;
  for (int c = 0; c < 64; c++) mu += rw[o * 64 + c] * (tot[4096 + c] * invM);
  float exx = 0.f;
  for (int c = 0; c < 64; c++) {
    const float* row = tot + c * 64;
    float p = 0.f;
    for (int c2 = 0; c2 < 64; c2++) p += rw[o * 64 + c2] * row[c2];
    exx += rw[o * 64 + c] * p;
  }
  exx *= invM;
  float var = exx - mu * mu;
  float mean = mu + rb[o];
  float sc = gam[o] / sqrtf(var + 1e-5f);
  bnsc[o] = sc;
  bnsh[o] = bet[o] - mean * sc;
}

// ---------------------------------------------------------------------------
// 8. node_fea = max_k relu(BN(W . fea[gidx2])). One block per (b,s).
//    W row per lane in registers; gathered features staged in LDS, float4 reads.
// ---------------------------------------------------------------------------
__global__ __launch_bounds__(256) void nodefea_kernel(const float* __restrict__ fea,
                                                      const float* __restrict__ rw,
                                                      const int* __restrict__ gidx2,
                                                      const float* __restrict__ bnsc,
                                                      const float* __restrict__ bnsh,
                                                      float* __restrict__ out_nf) {
  __shared__ __align__(16) float Lf[4096];  // [k][c]
  __shared__ float Lw[4096];                // [c][o] = rw[o][c]
  __shared__ int Lg[64];
  __shared__ float red[256];
  int bs = blockIdx.x, b = bs >> 6, s = bs & 63, t = threadIdx.x;
  if (t < 64) Lg[t] = gidx2[bs * 64 + t];
  __syncthreads();
  const float* fb = fea + (size_t)b * (CC * NN);
  for (int m = 0; m < 16; m++) {
    int idx = m * 256 + t;
    int k = idx >> 6, c = idx & 63;
    Lf[idx] = fb[(size_t)c * NN + Lg[k]];
    Lw[idx] = rw[(idx & 63) * 64 + (idx >> 6)];
  }
  __syncthreads();
  int o = t & 63, wq = t >> 6;
  float wreg[64];
#pragma unroll
  for (int c = 0; c < 64; c++) wreg[c] = Lw[c * 64 + o];
  float sc = bnsc[o], sh = bnsh[o];
  float mx = -1e30f;
  for (int k = wq * 16; k < wq * 16 + 16; k++) {
    float raw = 0.f;
#pragma unroll
    for (int c4 = 0; c4 < 16; c4++) {
      float4 lf = *(const float4*)&Lf[k * 64 + c4 * 4];
      raw = fmaf(wreg[4 * c4 + 0], lf.x, raw);
      raw = fmaf(wreg[4 * c4 + 1], lf.y, raw);
      raw = fmaf(wreg[4 * c4 + 2], lf.z, raw);
      raw = fmaf(wreg[4 * c4 + 3], lf.w, raw);
    }
    float v = raw * sc + sh;
    v = v > 0.f ? v : 0.f;
    mx = v > mx ? v : mx;
  }
  red[wq * 64 + o] = mx;
  __syncthreads();
  if (t < 64) {
    float m0 = red[t], m1 = red[64 + t], m2 = red[128 + t], m3 = red[192 + t];
    float ma = m0 > m1 ? m0 : m1;
    float mb = m2 > m3 ? m2 : m3;
    float m = ma > mb ? ma : mb;
    out_nf[b * 4096 + t * 64 + s] = m;   // node_fea[b][o=t][s]
  }
}

// ---------------------------------------------------------------------------
// 9. 3-NN inverse-distance interpolation + input_fea passthrough (output asm).
//    One thread per (b, n).
// ---------------------------------------------------------------------------
__global__ __launch_bounds__(256) void interp_kernel(const float* __restrict__ fea,
                                                     const float* __restrict__ loc,
                                                     const float* __restrict__ nloc,
                                                     const float* __restrict__ nf,
                                                     float* __restrict__ out) {
#pragma clang fp contract(off)
  int b = blockIdx.y;
  int t = threadIdx.x;
  int n = blockIdx.x * 256 + t;
  __shared__ float snl[192];
  __shared__ float sB[64];
  if (t < 192) snl[t] = nloc[b * 192 + t];
  __syncthreads();
  if (t < 64) {
    float x = snl[t * 3], y = snl[t * 3 + 1], z = snl[t * 3 + 2];
    sB[t] = (x * x + y * y) + z * z;
  }
  __syncthreads();
  const float* lb = loc + (size_t)b * 3 * NN;
  float px = lb[n], py = lb[NN + n], pz = lb[2 * NN + n];
  float A = (px * px + py * py) + pz * pz;
  float d0 = 1e30f, d1 = 1e30f, d2 = 1e30f;
  int i0 = 0, i1 = 0, i2 = 0;
  for (int s = 0; s < 64; s++) {
    float dot = fmaf(pz, snl[s * 3 + 2], fmaf(py, snl[s * 3 + 1], px * snl[s * 3]));
    float d = (A + sB[s]) - 2.0f * dot;
    if (d < d0) { d2 = d1; i2 = i1; d1 = d0; i1 = i0; d0 = d; i0 = s; }
    else if (d < d1) { d2 = d1; i2 = i1; d1 = d; i1 = s; }
    else if (d < d2) { d2 = d; i2 = s; }
  }
  d0 = d0 > 1e-10f ? d0 : 1e-10f;
  d1 = d1 > 1e-10f ? d1 : 1e-10f;
  d2 = d2 > 1e-10f ? d2 : 1e-10f;
  float r0 = 1.0f / d0, r1 = 1.0f / d1, r2 = 1.0f / d2;
  float rsum = (r0 + r1) + r2;
  float w0 = r0 / rsum, w1 = r1 / rsum, w2 = r2 / rsum;
  const float* nfb = nf + b * 4096;
  const float* fb = fea + (size_t)b * (CC * NN);
  float* ob = out + (size_t)b * (128 * NN);
  for (int o = 0; o < 64; o++) {
    ob[(size_t)o * NN + n] = fb[(size_t)o * NN + n];
    float ip = (nfb[o * 64 + i0] * w0 + nfb[o * 64 + i1] * w1) + nfb[o * 64 + i2] * w2;
    ob[(size_t)(64 + o) * NN + n] = ip;
  }
}

// ---------------------------------------------------------------------------
extern "C" void kernel_launch(void* const* d_in, const int* in_sizes, int n_in,
                              void* d_out, int out_size, void* d_ws, size_t ws_size,
                              hipStream_t stream) {
  (void)in_sizes; (void)n_in; (void)out_size; (void)ws_size;
  const float* fea = (const float*)d_in[0];
  const float* loc = (const float*)d_in[1];
  const float* pw  = (const float*)d_in[2];
  const float* rw  = (const float*)d_in[3];
  const float* rb  = (const float*)d_in[4];
  const float* gam = (const float*)d_in[5];
  const float* bet = (const float*)d_in[6];
  float* out = (float*)d_out;
  float* ws = (float*)d_ws;

  int*   fidx  = (int*)(ws + WS_FIDX);
  float* floc  = ws + WS_FLOC;
  float* ffea  = ws + WS_FFEA;
  int*   gidx  = (int*)(ws + WS_GIDX);
  float* nlocp = ws + WS_NLOC;
  int*   gidx2 = (int*)(ws + WS_GIDX2);
  float* part  = ws + WS_PART;
  float* tot   = ws + WS_TOT;
  float* bnsc  = ws + WS_SCALE;
  float* bnsh  = ws + WS_SHIFT;

  float* out_nf   = out + 33554432;  // node_fea   (B,64,64,1)
  float* out_noff = out + 33685504;  // node_offset(B,3,64)

  fps_kernel<<<dim3(32), dim3(256), 0, stream>>>(loc, fidx);
  gather_kernel<<<dim3(2048), dim3(64), 0, stream>>>(loc, fea, fidx, floc, ffea);
  ball1_kernel<<<dim3(512), dim3(256), 0, stream>>>(loc, floc, gidx);
  seman_kernel<<<dim3(2048), dim3(64), 0, stream>>>(fea, loc, pw, gidx, ffea, floc, out_noff, nlocp);
  knn_kernel<<<dim3(2048), dim3(256), 0, stream>>>(loc, nlocp, gidx2);
  cov_kernel<<<dim3(512), dim3(256), 0, stream>>>(fea, part);
  covreduce_kernel<<<dim3(17), dim3(256), 0, stream>>>(part, tot);
  bnstats_kernel<<<dim3(1), dim3(64), 0, stream>>>(tot, rw, rb, gam, bet, bnsc, bnsh);
  nodefea_kernel<<<dim3(2048), dim3(256), 0, stream>>>(fea, rw, gidx2, bnsc, bnsh, out_nf);
  interp_kernel<<<dim3(32, 32), dim3(256), 0, stream>>>(fea, loc, nlocp, out_nf, out);
}

// Round 3
// 660.987 us; speedup vs baseline: 1.2415x; 1.0882x over previous
//
#include <hip/hip_runtime.h>
#include <math.h>

// Problem constants
#define BB 32
#define NN 8192
#define CC 64
#define SS 64    // NUM_NODE
#define KK 64    // NSAMPLE

// Workspace layout (in floats)
#define WS_FIDX   0         // int[2048]
#define WS_FLOC   2048      // float[2048*3]
#define WS_FFEA   8192      // float[2048*64]
#define WS_GIDX   139264    // int[2048*64]
#define WS_NLOC   270336    // float[2048*3]
#define WS_GIDX2  276480    // int[2048*64]
#define WS_PART   407552    // float[512*4160]
#define WS_TOT    2537472   // float[4160]
#define WS_SCALE  2541632   // float[64]
#define WS_SHIFT  2541696   // float[64]

// ---------------------------------------------------------------------------
// 0. Transpose fea[b][c][n] -> feaT[b][n][c] (64 MB, lives in d_out scratch
//    until interp_kernel overwrites that region at the very end).
// ---------------------------------------------------------------------------
__global__ __launch_bounds__(256) void transpose_kernel(const float* __restrict__ fea,
                                                        float* __restrict__ feaT) {
  __shared__ float tile[64 * 65];
  int b = blockIdx.y;
  int n0 = blockIdx.x * 64;
  int t = threadIdx.x;
  const float* fb = fea + (size_t)b * (CC * NN);
#pragma unroll
  for (int m = 0; m < 16; m++) {
    int idx = m * 256 + t;
    int c = idx >> 6, nl = idx & 63;
    tile[c * 65 + nl] = fb[(size_t)c * NN + n0 + nl];
  }
  __syncthreads();
  float* ob = feaT + ((size_t)b * NN + n0) * 64;
#pragma unroll
  for (int m = 0; m < 16; m++) {
    int idx = m * 256 + t;
    int nl = idx >> 6, c = idx & 63;
    ob[idx] = tile[c * 65 + nl];
  }
}

// ---------------------------------------------------------------------------
// 1. Farthest point sampling: one block (512 thr) per batch. Points + dist in
//    statically-indexed registers (NO scratch spill); an LDS copy of the
//    points serves the uniform centroid lookup. One barrier per iteration
//    (parity double-buffered wave partials). Bitwise-exact reference math.
// ---------------------------------------------------------------------------
__global__ __launch_bounds__(512, 1) void fps_kernel(const float* __restrict__ loc,
                                                     int* __restrict__ fidx) {
#pragma clang fp contract(off)
  int b = blockIdx.x, t = threadIdx.x;
  const float* lb = loc + (size_t)b * 3 * NN;
  __shared__ float sx[NN], sy[NN], sz[NN];
  __shared__ float wrv[2][8];
  __shared__ int wri[2][8];
  float px[16], py[16], pz[16], dist[16];
#pragma unroll
  for (int k = 0; k < 16; k++) {
    int p = t + 512 * k;
    float x = lb[p], y = lb[NN + p], z = lb[2 * NN + p];
    px[k] = x; py[k] = y; pz[k] = z;
    sx[p] = x; sy[p] = y; sz[p] = z;
    dist[k] = 1e10f;
  }
  __syncthreads();
  int lane = t & 63, w = t >> 6;
  int far = 0;
  for (int it = 0; it < 64; it++) {
    if (t == 0) fidx[b * 64 + it] = far;
    float cx = sx[far], cy = sy[far], cz = sz[far];
    float bv = -1.0f; int bi = 0;
#pragma unroll
    for (int k = 0; k < 16; k++) {
      float dx = px[k] - cx, dy = py[k] - cy, dz = pz[k] - cz;
      float d = (dx * dx + dy * dy) + dz * dz;
      float dm = dist[k];
      dm = d < dm ? d : dm;
      dist[k] = dm;
      if (dm > bv) { bv = dm; bi = t + 512 * k; }   // ascending p: first-max kept
    }
    float v = bv; int vi = bi;
#pragma unroll
    for (int off = 1; off < 64; off <<= 1) {
      float v2 = __shfl_xor(v, off, 64);
      int   i2 = __shfl_xor(vi, off, 64);
      if (v2 > v || (v2 == v && i2 < vi)) { v = v2; vi = i2; }
    }
    int par = it & 1;
    if (lane == 0) { wrv[par][w] = v; wri[par][w] = vi; }
    __syncthreads();
    float gv = wrv[par][0]; int gi = wri[par][0];
#pragma unroll
    for (int w2 = 1; w2 < 8; w2++) {
      float v2 = wrv[par][w2]; int i2 = wri[par][w2];
      if (v2 > gv || (v2 == gv && i2 < gi)) { gv = v2; gi = i2; }
    }
    far = gi;   // identical on every thread
  }
}

// ---------------------------------------------------------------------------
// 2. Gather fpoint_loc / fpoint_fea
// ---------------------------------------------------------------------------
__global__ __launch_bounds__(64) void gather_kernel(const float* __restrict__ loc,
                                                    const float* __restrict__ fea,
                                                    const int* __restrict__ fidx,
                                                    float* __restrict__ floc,
                                                    float* __restrict__ ffea) {
  int bs = blockIdx.x, b = bs >> 6, c = threadIdx.x;
  int g = fidx[bs];
  ffea[bs * 64 + c] = fea[(size_t)b * (CC * NN) + (size_t)c * NN + g];
  if (c < 3) floc[bs * 3 + c] = loc[(size_t)b * (3 * NN) + (size_t)c * NN + g];
}

// ---------------------------------------------------------------------------
// 3. Ball query (radius): one wave per (b,s); ballot compaction, early exit.
// ---------------------------------------------------------------------------
__global__ __launch_bounds__(256) void ball1_kernel(const float* __restrict__ loc,
                                                    const float* __restrict__ floc,
                                                    int* __restrict__ gidx) {
#pragma clang fp contract(off)
  int w = threadIdx.x >> 6, lane = threadIdx.x & 63;
  int bs = blockIdx.x * 4 + w, b = bs >> 6;
  const float* lb = loc + (size_t)b * 3 * NN;
  float ax = floc[bs * 3], ay = floc[bs * 3 + 1], az = floc[bs * 3 + 2];
  float A = (ax * ax + ay * ay) + az * az;
  int count = 0, firsth = -1;
  for (int ch = 0; ch < 128 && count < 64; ch++) {
    int p = ch * 64 + lane;
    float bx = lb[p], by = lb[NN + p], bz = lb[2 * NN + p];
    float Bn = (bx * bx + by * by) + bz * bz;
    float dot = fmaf(az, bz, fmaf(ay, by, ax * bx));
    float sqr = (A + Bn) - 2.0f * dot;
    bool hit = !(sqr > 0.09f);
    unsigned long long m = __ballot(hit);
    if (m) {
      if (firsth < 0) firsth = ch * 64 + (int)__ffsll(m) - 1;
      int pos = count + (int)__popcll(m & ((1ull << lane) - 1ull));
      if (hit && pos < 64) gidx[bs * 64 + pos] = p;
      count += (int)__popcll(m);
    }
  }
  if (count < 64 && lane >= count) gidx[bs * 64 + lane] = firsth;
}

// ---------------------------------------------------------------------------
// 4. seman/node_offset/node_loc. One wave per (b,s), lane = k. Features
//    gathered from feaT (contiguous 256B per point, float4).
// ---------------------------------------------------------------------------
__global__ __launch_bounds__(64) void seman_kernel(const float* __restrict__ feaT,
                                                   const float* __restrict__ loc,
                                                   const float* __restrict__ pw,
                                                   const int* __restrict__ gidx,
                                                   const float* __restrict__ ffea,
                                                   const float* __restrict__ floc,
                                                   float* __restrict__ out_noff,
                                                   float* __restrict__ nloc) {
  int bs = blockIdx.x, b = bs >> 6, s = bs & 63, k = threadIdx.x;
  __shared__ float sf[64];
  __shared__ float spw[192];
  __shared__ float sl[3];
  sf[k] = ffea[bs * 64 + k];
  spw[k] = pw[k]; spw[64 + k] = pw[64 + k]; spw[128 + k] = pw[128 + k];
  if (k < 3) sl[k] = floc[bs * 3 + k];
  __syncthreads();
  int g = gidx[bs * 64 + k];
  const float* fT = feaT + ((size_t)b * NN + g) * 64;
  float a0 = 0.f, a1 = 0.f, a2 = 0.f;
#pragma unroll
  for (int c4 = 0; c4 < 16; c4++) {
    float4 f = *(const float4*)(fT + 4 * c4);
    int c = 4 * c4;
    float g0 = f.x - sf[c + 0];
    a0 = fmaf(spw[c + 0], g0, a0); a1 = fmaf(spw[64 + c + 0], g0, a1); a2 = fmaf(spw[128 + c + 0], g0, a2);
    float g1 = f.y - sf[c + 1];
    a0 = fmaf(spw[c + 1], g1, a0); a1 = fmaf(spw[64 + c + 1], g1, a1); a2 = fmaf(spw[128 + c + 1], g1, a2);
    float g2 = f.z - sf[c + 2];
    a0 = fmaf(spw[c + 2], g2, a0); a1 = fmaf(spw[64 + c + 2], g2, a1); a2 = fmaf(spw[128 + c + 2], g2, a2);
    float g3 = f.w - sf[c + 3];
    a0 = fmaf(spw[c + 3], g3, a0); a1 = fmaf(spw[64 + c + 3], g3, a1); a2 = fmaf(spw[128 + c + 3], g3, a2);
  }
  const float* lb = loc + (size_t)b * 3 * NN;
  float c0 = tanhf(a0) * (lb[g] - sl[0]);
  float c1 = tanhf(a1) * (lb[NN + g] - sl[1]);
  float c2 = tanhf(a2) * (lb[2 * NN + g] - sl[2]);
#pragma unroll
  for (int off = 32; off; off >>= 1) {
    c0 += __shfl_xor(c0, off, 64);
    c1 += __shfl_xor(c1, off, 64);
    c2 += __shfl_xor(c2, off, 64);
  }
  if (k == 0) {
    float m0 = c0 * (1.0f / 64), m1 = c1 * (1.0f / 64), m2 = c2 * (1.0f / 64);
    out_noff[b * 192 + s] = m0;
    out_noff[b * 192 + 64 + s] = m1;
    out_noff[b * 192 + 128 + s] = m2;
    nloc[bs * 3 + 0] = sl[0] + m0;
    nloc[bs * 3 + 1] = sl[1] + m1;
    nloc[bs * 3 + 2] = sl[2] + m2;
  }
}

// ---------------------------------------------------------------------------
// 5. kNN-64 via radix select (set semantics; (key,index) lexicographic ties).
// ---------------------------------------------------------------------------
__global__ __launch_bounds__(256) void knn_kernel(const float* __restrict__ loc,
                                                  const float* __restrict__ nloc,
                                                  int* __restrict__ gidx2) {
#pragma clang fp contract(off)
  int bs = blockIdx.x, b = bs >> 6, t = threadIdx.x;
  const float* lb = loc + (size_t)b * 3 * NN;
  float ax = nloc[bs * 3], ay = nloc[bs * 3 + 1], az = nloc[bs * 3 + 2];
  float A = (ax * ax + ay * ay) + az * az;
  __shared__ unsigned keys[NN];
  __shared__ unsigned hist[4096];          // reused as u16 cand[8192] later
  __shared__ unsigned part[256];
  __shared__ int sP, sC0, nOut, nCand;
  for (int m = 0; m < 16; m++) hist[m * 256 + t] = 0u;
  if (t == 0) { nOut = 0; nCand = 0; }
  __syncthreads();
  unsigned mykey[32];
#pragma unroll
  for (int k = 0; k < 32; k++) {
    int p = t + 256 * k;
    float bx = lb[p], by = lb[NN + p], bz = lb[2 * NN + p];
    float Bn = (bx * bx + by * by) + bz * bz;
    float dot = fmaf(az, bz, fmaf(ay, by, ax * bx));
    float d = (A + Bn) - 2.0f * dot;
    unsigned kb = __float_as_uint(d);
    kb = (kb & 0x80000000u) ? ~kb : (kb | 0x80000000u);   // monotonic transform
    mykey[k] = kb;
    keys[p] = kb;
    atomicAdd(&hist[kb >> 20], 1u);
  }
  __syncthreads();
  unsigned ps = 0;
#pragma unroll
  for (int m = 0; m < 16; m++) ps += hist[t * 16 + m];
  part[t] = ps;
  __syncthreads();
  if (t == 0) {
    int cum = 0, seg = 0;
    for (int t2 = 0; t2 < 256; t2++) {
      if (cum + (int)part[t2] >= 64) { seg = t2; break; }
      cum += (int)part[t2];
    }
    int P = seg * 16;
    for (;; P++) {
      if (cum + (int)hist[P] >= 64) break;
      cum += (int)hist[P];
    }
    sP = P; sC0 = cum;
  }
  __syncthreads();
  int P = sP, C0 = sC0;
  unsigned short* cand = (unsigned short*)hist;   // hist dead past this point
  __syncthreads();                                 // protect reuse
#pragma unroll
  for (int k = 0; k < 32; k++) {
    int bin = (int)(mykey[k] >> 20);
    if (bin < P) {
      int pos = atomicAdd(&nOut, 1);
      gidx2[bs * 64 + pos] = t + 256 * k;
    } else if (bin == P) {
      int c = atomicAdd(&nCand, 1);
      cand[c] = (unsigned short)(t + 256 * k);
    }
  }
  __syncthreads();
  if (t < 64) {
    int lane = t;
    int R = 64 - C0, nC = nCand;
    for (int r = 0; r < R; r++) {
      unsigned bk = 0xFFFFFFFFu; int bp = 0x7FFFFFFF, bj = -1;
      for (int j = lane; j < nC; j += 64) {
        int p = cand[j];
        if (p != 0xFFFF) {
          unsigned k2 = keys[p];
          if (k2 < bk || (k2 == bk && p < bp)) { bk = k2; bp = p; bj = j; }
        }
      }
#pragma unroll
      for (int off = 1; off < 64; off <<= 1) {
        unsigned k2 = __shfl_xor(bk, off, 64);
        int p2 = __shfl_xor(bp, off, 64);
        int j2 = __shfl_xor(bj, off, 64);
        if (k2 < bk || (k2 == bk && p2 < bp)) { bk = k2; bp = p2; bj = j2; }
      }
      if (lane == 0) {
        gidx2[bs * 64 + C0 + r] = bp;
        cand[bj] = 0xFFFF;
      }
      __threadfence_block();
    }
  }
}

// ---------------------------------------------------------------------------
// 6. Input channel covariance (for BN stats of the linear layer).
// ---------------------------------------------------------------------------
__global__ __launch_bounds__(256) void cov_kernel(const float* __restrict__ fea,
                                                  float* __restrict__ part) {
  __shared__ float Sf[64 * 133];
  __shared__ float red[4160];
  int t = threadIdx.x, w = t >> 6, lane = t & 63;
  int i = lane >> 3, j = lane & 7;
  float acc[8][8];
  float rs[8];
#pragma unroll
  for (int r = 0; r < 8; r++) {
    rs[r] = 0.f;
#pragma unroll
    for (int r2 = 0; r2 < 8; r2++) acc[r][r2] = 0.f;
  }
  for (int q = 0; q < 4; q++) {
    int chunk = blockIdx.x * 4 + q;
    int p0 = chunk * 128;
    int b = p0 >> 13, n0 = p0 & 8191;
    __syncthreads();
    const float* fb = fea + (size_t)b * (CC * NN) + n0;
    for (int m = 0; m < 32; m++) {
      int idx = m * 256 + t;
      int c = idx >> 7, pt = idx & 127;
      Sf[c * 133 + pt] = fb[(size_t)c * NN + pt];
    }
    __syncthreads();
    for (int pt = w * 32; pt < w * 32 + 32; pt++) {
      float a[8], bv[8];
#pragma unroll
      for (int r = 0; r < 8; r++) {
        a[r] = Sf[(8 * i + r) * 133 + pt];
        bv[r] = Sf[(8 * j + r) * 133 + pt];
      }
#pragma unroll
      for (int r = 0; r < 8; r++) {
        rs[r] += a[r];
#pragma unroll
        for (int r2 = 0; r2 < 8; r2++) acc[r][r2] = fmaf(a[r], bv[r2], acc[r][r2]);
      }
    }
  }
  for (int ww = 0; ww < 4; ww++) {
    if (w == ww) {
#pragma unroll
      for (int r = 0; r < 8; r++) {
#pragma unroll
        for (int r2 = 0; r2 < 8; r2++) {
          int idx = (8 * i + r) * 64 + 8 * j + r2;
          if (ww == 0) red[idx] = acc[r][r2]; else red[idx] += acc[r][r2];
        }
        if (j == 0) {
          int ridx = 4096 + 8 * i + r;
          if (ww == 0) red[ridx] = rs[r]; else red[ridx] += rs[r];
        }
      }
    }
    __syncthreads();
  }
  float* pb = part + (size_t)blockIdx.x * 4160;
  for (int idx = t; idx < 4160; idx += 256) pb[idx] = red[idx];
}

__global__ __launch_bounds__(256) void covreduce_kernel(const float* __restrict__ part,
                                                        float* __restrict__ tot) {
  int e = blockIdx.x * 256 + threadIdx.x;
  if (e >= 4160) return;
  float s = 0.f;
  for (int b2 = 0; b2 < 512; b2++) s += part[(size_t)b2 * 4160 + e];
  tot[e] = s;
}

// ---------------------------------------------------------------------------
// 7. BN stats from channel moments.
// ---------------------------------------------------------------------------
__global__ __launch_bounds__(64) void bnstats_kernel(const float* __restrict__ tot,
                                                     const float* __restrict__ rw,
                                                     const float* __restrict__ rb,
                                                     const float* __restrict__ gam,
                                                     const float* __restrict__ bet,
                                                     float* __restrict__ bnsc,
                                                     float* __restrict__ bnsh) {
  int o = threadIdx.x;
  const float invM = 1.0f / 262144.0f;
  float mu = 0.f;
  for (int c = 0; c < 64; c++) mu += rw[o * 64 + c] * (tot[4096 + c] * invM);
  float exx = 0.f;
  for (int c = 0; c < 64; c++) {
    const float* row = tot + c * 64;
    float p = 0.f;
    for (int c2 = 0; c2 < 64; c2++) p += rw[o * 64 + c2] * row[c2];
    exx += rw[o * 64 + c] * p;
  }
  exx *= invM;
  float var = exx - mu * mu;
  float mean = mu + rb[o];
  float sc = gam[o] / sqrtf(var + 1e-5f);
  bnsc[o] = sc;
  bnsh[o] = bet[o] - mean * sc;
}

// ---------------------------------------------------------------------------
// 8. node_fea = max_k relu(BN(W . fea[gidx2])). Gather via feaT (coalesced).
// ---------------------------------------------------------------------------
__global__ __launch_bounds__(256) void nodefea_kernel(const float* __restrict__ feaT,
                                                      const float* __restrict__ rw,
                                                      const int* __restrict__ gidx2,
                                                      const float* __restrict__ bnsc,
                                                      const float* __restrict__ bnsh,
                                                      float* __restrict__ out_nf) {
  __shared__ __align__(16) float Lf[4096];  // [k][c]
  __shared__ float Lw[4096];                // [c][o] = rw[o][c]
  __shared__ int Lg[64];
  __shared__ float red[256];
  int bs = blockIdx.x, b = bs >> 6, s = bs & 63, t = threadIdx.x;
  if (t < 64) Lg[t] = gidx2[bs * 64 + t];
  __syncthreads();
#pragma unroll
  for (int m = 0; m < 4; m++) {
    int idx4 = m * 256 + t;               // 1024 float4s
    int k = idx4 >> 4, c4 = idx4 & 15;
    float4 f = *(const float4*)(feaT + ((size_t)b * NN + Lg[k]) * 64 + 4 * c4);
    *(float4*)&Lf[idx4 * 4] = f;
  }
  for (int m = 0; m < 16; m++) {
    int idx = m * 256 + t;
    Lw[idx] = rw[(idx & 63) * 64 + (idx >> 6)];
  }
  __syncthreads();
  int o = t & 63, wq = t >> 6;
  float wreg[64];
#pragma unroll
  for (int c = 0; c < 64; c++) wreg[c] = Lw[c * 64 + o];
  float sc = bnsc[o], sh = bnsh[o];
  float mx = -1e30f;
  for (int k = wq * 16; k < wq * 16 + 16; k++) {
    float raw = 0.f;
#pragma unroll
    for (int c4 = 0; c4 < 16; c4++) {
      float4 lf = *(const float4*)&Lf[k * 64 + c4 * 4];
      raw = fmaf(wreg[4 * c4 + 0], lf.x, raw);
      raw = fmaf(wreg[4 * c4 + 1], lf.y, raw);
      raw = fmaf(wreg[4 * c4 + 2], lf.z, raw);
      raw = fmaf(wreg[4 * c4 + 3], lf.w, raw);
    }
    float v = raw * sc + sh;
    v = v > 0.f ? v : 0.f;
    mx = v > mx ? v : mx;
  }
  red[wq * 64 + o] = mx;
  __syncthreads();
  if (t < 64) {
    float m0 = red[t], m1 = red[64 + t], m2 = red[128 + t], m3 = red[192 + t];
    float ma = m0 > m1 ? m0 : m1;
    float mb = m2 > m3 ? m2 : m3;
    float m = ma > mb ? ma : mb;
    out_nf[b * 4096 + t * 64 + s] = m;   // node_fea[b][o=t][s]
  }
}

// ---------------------------------------------------------------------------
// 9. 3-NN inverse-distance interpolation + input_fea passthrough.
// ---------------------------------------------------------------------------
__global__ __launch_bounds__(256) void interp_kernel(const float* __restrict__ fea,
                                                     const float* __restrict__ loc,
                                                     const float* __restrict__ nloc,
                                                     const float* __restrict__ nf,
                                                     float* __restrict__ out) {
#pragma clang fp contract(off)
  int b = blockIdx.y;
  int t = threadIdx.x;
  int n = blockIdx.x * 256 + t;
  __shared__ float snl[192];
  __shared__ float sB[64];
  if (t < 192) snl[t] = nloc[b * 192 + t];
  __syncthreads();
  if (t < 64) {
    float x = snl[t * 3], y = snl[t * 3 + 1], z = snl[t * 3 + 2];
    sB[t] = (x * x + y * y) + z * z;
  }
  __syncthreads();
  const float* lb = loc + (size_t)b * 3 * NN;
  float px = lb[n], py = lb[NN + n], pz = lb[2 * NN + n];
  float A = (px * px + py * py) + pz * pz;
  float d0 = 1e30f, d1 = 1e30f, d2 = 1e30f;
  int i0 = 0, i1 = 0, i2 = 0;
  for (int s = 0; s < 64; s++) {
    float dot = fmaf(pz, snl[s * 3 + 2], fmaf(py, snl[s * 3 + 1], px * snl[s * 3]));
    float d = (A + sB[s]) - 2.0f * dot;
    if (d < d0) { d2 = d1; i2 = i1; d1 = d0; i1 = i0; d0 = d; i0 = s; }
    else if (d < d1) { d2 = d1; i2 = i1; d1 = d; i1 = s; }
    else if (d < d2) { d2 = d; i2 = s; }
  }
  d0 = d0 > 1e-10f ? d0 : 1e-10f;
  d1 = d1 > 1e-10f ? d1 : 1e-10f;
  d2 = d2 > 1e-10f ? d2 : 1e-10f;
  float r0 = 1.0f / d0, r1 = 1.0f / d1, r2 = 1.0f / d2;
  float rsum = (r0 + r1) + r2;
  float w0 = r0 / rsum, w1 = r1 / rsum, w2 = r2 / rsum;
  const float* nfb = nf + b * 4096;
  const float* fb = fea + (size_t)b * (CC * NN);
  float* ob = out + (size_t)b * (128 * NN);
  for (int o = 0; o < 64; o++) {
    ob[(size_t)o * NN + n] = fb[(size_t)o * NN + n];
    float ip = (nfb[o * 64 + i0] * w0 + nfb[o * 64 + i1] * w1) + nfb[o * 64 + i2] * w2;
    ob[(size_t)(64 + o) * NN + n] = ip;
  }
}

// ---------------------------------------------------------------------------
extern "C" void kernel_launch(void* const* d_in, const int* in_sizes, int n_in,
                              void* d_out, int out_size, void* d_ws, size_t ws_size,
                              hipStream_t stream) {
  (void)in_sizes; (void)n_in; (void)out_size; (void)ws_size;
  const float* fea = (const float*)d_in[0];
  const float* loc = (const float*)d_in[1];
  const float* pw  = (const float*)d_in[2];
  const float* rw  = (const float*)d_in[3];
  const float* rb  = (const float*)d_in[4];
  const float* gam = (const float*)d_in[5];
  const float* bet = (const float*)d_in[6];
  float* out = (float*)d_out;
  float* ws = (float*)d_ws;

  int*   fidx  = (int*)(ws + WS_FIDX);
  float* floc  = ws + WS_FLOC;
  float* ffea  = ws + WS_FFEA;
  int*   gidx  = (int*)(ws + WS_GIDX);
  float* nlocp = ws + WS_NLOC;
  int*   gidx2 = (int*)(ws + WS_GIDX2);
  float* part  = ws + WS_PART;
  float* tot   = ws + WS_TOT;
  float* bnsc  = ws + WS_SCALE;
  float* bnsh  = ws + WS_SHIFT;

  float* feaT     = out;             // 64 MB scratch; overwritten by interp last
  float* out_nf   = out + 33554432;  // node_fea   (B,64,64,1)
  float* out_noff = out + 33685504;  // node_offset(B,3,64)

  transpose_kernel<<<dim3(128, 32), dim3(256), 0, stream>>>(fea, feaT);
  fps_kernel<<<dim3(32), dim3(512), 0, stream>>>(loc, fidx);
  gather_kernel<<<dim3(2048), dim3(64), 0, stream>>>(loc, fea, fidx, floc, ffea);
  ball1_kernel<<<dim3(512), dim3(256), 0, stream>>>(loc, floc, gidx);
  seman_kernel<<<dim3(2048), dim3(64), 0, stream>>>(feaT, loc, pw, gidx, ffea, floc, out_noff, nlocp);
  knn_kernel<<<dim3(2048), dim3(256), 0, stream>>>(loc, nlocp, gidx2);
  cov_kernel<<<dim3(512), dim3(256), 0, stream>>>(fea, part);
  covreduce_kernel<<<dim3(17), dim3(256), 0, stream>>>(part, tot);
  bnstats_kernel<<<dim3(1), dim3(64), 0, stream>>>(tot, rw, rb, gam, bet, bnsc, bnsh);
  nodefea_kernel<<<dim3(2048), dim3(256), 0, stream>>>(feaT, rw, gidx2, bnsc, bnsh, out_nf);
  interp_kernel<<<dim3(32, 32), dim3(256), 0, stream>>>(fea, loc, nlocp, out_nf, out);
}